// Round 9
// baseline (210.551 us; speedup 1.0000x reference)
//
#include <hip/hip_runtime.h>
#include <math.h>

// B=128, N=64, D=2, H=64, M=64, L=2. f32 in / f32 out.
// R26 = R25 (WIN: 205.6us, k_L0 57.9) with k_L0/k_L1 at 512 threads/block:
// 8 waves, waves 0-3 own tiles {0,1} (j0,j1), waves 4-7 own tiles {2,3}
// (j2,j3). Same 4-j amortization + LDS (37.9KB, aliased sred/shv), but
// 32 waves/CU instead of 16.
// Why: R25 counters showed Occupancy 48->31%, VALUBusy 76 (down from 84) —
// amortization gain was partly eaten by lost latency hiding. This decouples
// j-count (VALU amortization) from wave count (TLP): per-thread VALU halves
// back to R24 level, total issue unchanged, stall fraction should shrink.
// Prediction: Occ ~55-65%, VALUBusy 85-90, k_L0 51-54, k_L1 -3-5,
// total ~193-199. Falsify: k_L0 >= 57 -> VALU-issue floor reached; next
// lever = packed-f16 gelu or accept ceiling.
// Session model: k_L0 VALU ~2x naive hand-count is REAL (gelu ~11 instr x
// 192/thread at 4j dominates). Launch slots ~14us x 4 (fusion dead: R15/16/
// R22 coherence poison). Container noise +-7%/kernel.
// DEAD BRANCHES: cross-block coherence tails; VGPR-cap theory (R23);
// intra-phase trimming alone (R19, pre-saturation).
// Merged weights: SA=ew2@w1he0, SB=w2_0@u1_0(+biasB), SC=w2_0@w1he1, SD=w2_1@u1_1(+biasD);
// p0' carries b1_0+eb2@w1he0; p1' carries b1n+b2_0@w1he1 (biasC).
// MFMA fragment addressing identical to R9-R14 (verified).

typedef unsigned short u16;
typedef unsigned int u32;
typedef _Float16 half8 __attribute__((ext_vector_type(8)));   // 4 VGPR frag
typedef __attribute__((ext_vector_type(4))) float floatx4;

#define TS 72            // LDS tile row stride (f16): 144 B
#define HROW 72          // he0g row stride (u16) — mirrors LDS tile
#define HBLK (64 * HROW) // 4608 u16 per (b,j) tile
#define TILEB (64 * TS * 2)  // 9216 B per LDS tile

// gelu via A&S 7.1.27 rational erf (|eps|<=5e-4), no exp (R14-verified)
__device__ __forceinline__ float gelu_f(float x) {
    float s = fabsf(x) * 0.70710678118654752f;
    float q = fmaf(fmaf(fmaf(fmaf(0.078108f, s, 0.000972f), s, 0.230389f), s, 0.278393f), s, 1.0f);
    float q2 = q * q;
    float r = __builtin_amdgcn_rcpf(q2 * q2);
    float t = 0.5f * x * r;
    return x > 0.f ? x - t : t;
}

// k_pre: unchanged from R21 (verified).
__global__ __launch_bounds__(256) void k_pre(
    const float* __restrict__ ew2, const float* __restrict__ w1he0,
    const float* __restrict__ w2_0, const float* __restrict__ u1_0,
    const float* __restrict__ w1he1, const float* __restrict__ w2_1,
    const float* __restrict__ u1_1,
    const float* __restrict__ eb2, const float* __restrict__ b2_0,
    const float* __restrict__ c1_0, const float* __restrict__ b2_1,
    const float* __restrict__ c1_1,
    const float* __restrict__ b1_0v, const float* __restrict__ b1nv,
    const float* __restrict__ u2_0, const float* __restrict__ u2_1,
    const float* __restrict__ w1n, const float* __restrict__ hw1,
    _Float16* __restrict__ WF,
    float* __restrict__ biasB, float* __restrict__ biasC, float* __restrict__ biasD,
    float* __restrict__ u2_0T, float* __restrict__ u2_1T,
    float* __restrict__ w1nT, float* __restrict__ hw1T,
    const float* __restrict__ x, const float* __restrict__ spin,
    const float* __restrict__ nw1, const float* __restrict__ nb1,
    const float* __restrict__ nw2, const float* __restrict__ nb2,
    const float* __restrict__ w1_0,
    float* __restrict__ hv, float* __restrict__ p0)
{
    int blk = blockIdx.x;
    if (blk < 64) {
        int s = blk >> 4;                               // product id
        int idx = (blk & 15) * 256 + threadIdx.x;       // 0..4095
        int k = idx >> 6, n = idx & 63;
        const float *A, *Bm;
        if (s == 0)      { A = ew2;  Bm = w1he0; }
        else if (s == 1) { A = w2_0; Bm = u1_0;  }
        else if (s == 2) { A = w2_0; Bm = w1he1; }
        else             { A = w2_1; Bm = u1_1;  }
        float acc = 0.f;
        for (int q = 0; q < 64; ++q) acc = fmaf(A[k * 64 + q], Bm[q * 64 + n], acc);
        int kc = k >> 5, qd = (k >> 3) & 3, jj = k & 7;
        WF[(((s * 2 + kc) * 64 + n) * 4 + qd) * 8 + jj] = (_Float16)acc;
    } else if (blk == 64) {
        int s = threadIdx.x >> 6, cc = threadIdx.x & 63;
        if (s > 0) {
            const float *bv, *Bm, *add; float* dst;
            if (s == 1)      { bv = b2_0; Bm = u1_0;  add = c1_0; dst = biasB; }
            else if (s == 2) { bv = b2_0; Bm = w1he1; add = b1nv; dst = biasC; }
            else             { bv = b2_1; Bm = u1_1;  add = c1_1; dst = biasD; }
            float acc = add[cc];
            for (int q = 0; q < 64; ++q) acc = fmaf(bv[q], Bm[q * 64 + cc], acc);
            dst[cc] = acc;
        }
    } else if (blk < 129) {
        int idx = (blk - 65) * 256 + threadIdx.x;       // 0..16383
        int s = idx >> 12, r = idx & 4095, m = r >> 6, tc = r & 63;
        const float* W = s == 0 ? u2_0 : s == 1 ? u2_1 : s == 2 ? w1n : hw1;
        float* WT      = s == 0 ? u2_0T : s == 1 ? u2_1T : s == 2 ? w1nT : hw1T;
        WT[tc * 64 + m] = W[m * 64 + tc];
    } else {
        __shared__ float a[4][64];
        __shared__ float shv[4][64];
        int w = threadIdx.x >> 6, h = threadIdx.x & 63;
        int node = (blk - 129) * 4 + w;
        float2 xv = ((const float2*)x)[node];
        float sp = spin[node];
        float z = fmaf(xv.x, nw1[h], fmaf(xv.y, nw1[64 + h], fmaf(sp, nw1[128 + h], nb1[h])));
        a[w][h] = gelu_f(z);                         // wave-synchronous slice
        float acc = nb2[h];
        for (int k = 0; k < 64; ++k) acc = fmaf(a[w][k], nw2[k * 64 + h], acc);
        hv[node * 64 + h] = acc;
        shv[w][h] = acc;
        // p0' = b1_0 + eb2@w1he0 (biasA fold, inline) + hv@w1_0
        float pa = b1_0v[h];
        for (int q = 0; q < 64; ++q) pa = fmaf(eb2[q], w1he0[q * 64 + h], pa);
        for (int k = 0; k < 64; ++k) pa = fmaf(shv[w][k], w1_0[k * 64 + h], pa);
        p0[node * 64 + h] = pa;
    }
}

// dual-tile MFMA: shared B-fragment, two A-tiles (R9-verified addressing)
__device__ __forceinline__ void mfma_acc2(
    const _Float16* __restrict__ tA0, const _Float16* __restrict__ tA1,
    const _Float16* __restrict__ WF,
    int stage, int c, int quad, int nn, floatx4 acc0[4], floatx4 acc1[4])
{
    int sA = ((nn >> 2) & 3) << 3;
    #pragma unroll
    for (int kc = 0; kc < 2; ++kc) {
        half8 bf = *(const half8*)(WF + (((stage * 2 + kc) * 64 + c) * 4 + quad) * 8);
        int k0 = (kc * 32 + quad * 8) ^ sA;
        #pragma unroll
        for (int mt = 0; mt < 4; ++mt) {
            int off = (mt * 16 + nn) * TS + k0;
            acc0[mt] = __builtin_amdgcn_mfma_f32_16x16x32_f16(*(const half8*)(tA0 + off), bf, acc0[mt], 0, 0, 0);
            acc1[mt] = __builtin_amdgcn_mfma_f32_16x16x32_f16(*(const half8*)(tA1 + off), bf, acc1[mt], 0, 0, 0);
        }
    }
}

__device__ __forceinline__ void init_bias(floatx4 acc[4], float bc) {
    #pragma unroll
    for (int mt = 0; mt < 4; ++mt) acc[mt] = (floatx4){bc, bc, bc, bc};
}
__device__ __forceinline__ void init_p(floatx4 acc[4], const float* __restrict__ p,
                                       int rowbase, int c, int quad) {
    #pragma unroll
    for (int mt = 0; mt < 4; ++mt)
        #pragma unroll
        for (int r = 0; r < 4; ++r)
            acc[mt][r] = p[(rowbase + mt * 16 + quad * 4 + r) * 64 + c];
}

// 512 threads: group g = wave>>2 owns tiles {2g, 2g+1} = j's {jp*4+2g, +1}.
__global__ __launch_bounds__(512, 8) void k_L0(
    const float* __restrict__ x,
    const float* __restrict__ ew1, const float* __restrict__ eb1,
    const float* __restrict__ p0,        // p0' (biasA folded), per (b,i)
    const float* __restrict__ biasB,
    const float* __restrict__ u2_0T, const float* __restrict__ c2_0,
    const _Float16* __restrict__ WF,
    const float* __restrict__ hv0, float* __restrict__ hv1,
    const float* __restrict__ w1nT, const float* __restrict__ biasC,
    float* __restrict__ p1,
    u16* __restrict__ he0g)
{
    __shared__ __align__(16) char smem[4 * TILEB + 1024];   // 37.9 KB
    float* sS   = (float*)(smem + 4 * TILEB);   // [4][64], dedicated
    float* sred = (float*)smem;                  // [4][256] aliases tile0 (barrier-protected)
    float* shv  = (float*)(smem + TILEB);        // [4][64]  aliases tile1 (barrier-protected)

    int t = threadIdx.x, L = t & 63;
    int wl = __builtin_amdgcn_readfirstlane((t >> 6) & 3);  // wave within group
    int g  = __builtin_amdgcn_readfirstlane(t >> 8);        // group 0/1
    int nn = L & 15, quad = L >> 4;
    int c = wl * 16 + nn;
    int cw = c ^ (quad << 3);
    int b = blockIdx.x >> 4, jp = blockIdx.x & 15;
    int ja = jp * 4 + g * 2, jb = ja + 1;
    _Float16* tX0 = (_Float16*)(smem + (2 * g) * TILEB);
    _Float16* tX1 = (_Float16*)(smem + (2 * g + 1) * TILEB);

    // geometry: lane = i = L; this group's two destinations
    float2 xi = ((const float2*)x)[b * 64 + L];
    float2 xa = ((const float2*)x)[b * 64 + ja];
    float2 xb = ((const float2*)x)[b * 64 + jb];
    float da0 = xa.x - xi.x, da1 = xa.y - xi.y;
    float r2a = fmaf(da0, da0, da1 * da1), rra = sqrtf(r2a + 1e-12f);
    float db0 = xb.x - xi.x, db1 = xb.y - xi.y;
    float r2b = fmaf(db0, db0, db1 * db1), rrb = sqrtf(r2b + 1e-12f);
    int swL = ((L >> 2) & 3) << 3;

    // g1 rows for both j's of this group
    #pragma unroll
    for (int mb = 0; mb < 2; ++mb) {
        int m0 = wl * 16 + mb * 8;
        half8 h8a, h8b;
        #pragma unroll
        for (int kk = 0; kk < 8; ++kk) {
            int m = m0 + kk;
            float e0 = ew1[m], e1 = ew1[64 + m], e2 = ew1[128 + m], e3 = ew1[192 + m], e4 = eb1[m];
            h8a[kk] = (_Float16)gelu_f(fmaf(da0, e0, fmaf(da1, e1, fmaf(rra, e2, fmaf(r2a, e3, e4)))));
            h8b[kk] = (_Float16)gelu_f(fmaf(db0, e0, fmaf(db1, e1, fmaf(rrb, e2, fmaf(r2b, e3, e4)))));
        }
        int o = L * TS + (m0 ^ swL);
        *(half8*)(tX0 + o) = h8a;
        *(half8*)(tX1 + o) = h8b;
    }
    __syncthreads();                                  // (1) g1 ready

    floatx4 acc0[4], acc1[4];
    // M1: z0 = p0' + g1 @ SA (p0 rows shared across j)
    init_p(acc0, p0, b * 64, c, quad);
    #pragma unroll
    for (int mt = 0; mt < 4; ++mt) acc1[mt] = acc0[mt];
    mfma_acc2(tX0, tX1, WF, 0, c, quad, nn, acc0, acc1);
    __syncthreads();                                  // (2) tile reads done
    #pragma unroll
    for (int mt = 0; mt < 4; ++mt)
        #pragma unroll
        for (int r = 0; r < 4; ++r) {
            int i = mt * 16 + quad * 4 + r;
            tX0[i * TS + cw] = (_Float16)gelu_f(acc0[mt][r]);
            tX1[i * TS + cw] = (_Float16)gelu_f(acc1[mt][r]);
        }
    __syncthreads();                                  // (3) Y visible
    // he0g: linear b128 copy of all 4 tiles (pads incl., never read; R19-safe)
    {
        float4* dst = (float4*)(he0g + (size_t)(b * 64 + jp * 4) * HBLK);
        const float4* src = (const float4*)smem;
        for (int q = t; q < 2304; q += 512) dst[q] = src[q];
    }
    // M2: a = gelu(Y @ SB + biasB); masked i-sums
    {
        float bb = biasB[c];
        init_bias(acc0, bb); init_bias(acc1, bb);
    }
    mfma_acc2(tX0, tX1, WF, 1, c, quad, nn, acc0, acc1);
    {
        float s0 = 0.f, s1 = 0.f;
        #pragma unroll
        for (int mt = 0; mt < 4; ++mt)
            #pragma unroll
            for (int r = 0; r < 4; ++r) {
                int i = mt * 16 + quad * 4 + r;
                s0 += (i == ja) ? 0.f : gelu_f(acc0[mt][r]);
                s1 += (i == jb) ? 0.f : gelu_f(acc1[mt][r]);
            }
        s0 += __shfl_xor(s0, 16); s0 += __shfl_xor(s0, 32);
        s1 += __shfl_xor(s1, 16); s1 += __shfl_xor(s1, 32);
        if (quad == 0) { sS[(2 * g) * 64 + c] = s0; sS[(2 * g + 1) * 64 + c] = s1; }
    }
    __syncthreads();                                  // (4) sS ready; tiles dead -> aliases live
    // tail A: hv1 dots, u2_0T columns shared
    {
        const float4* uv4 = (const float4*)(u2_0T + L * 64 + wl * 16);
        const float4* sv0 = (const float4*)(sS + (2 * g) * 64 + wl * 16);
        const float4* sv1 = (const float4*)(sS + (2 * g + 1) * 64 + wl * 16);
        float g0 = 0.f, g1v = 0.f;
        #pragma unroll
        for (int m4 = 0; m4 < 4; ++m4) {
            float4 uv = uv4[m4], v0 = sv0[m4], v1 = sv1[m4];
            g0  = fmaf(v0.x, uv.x, fmaf(v0.y, uv.y, fmaf(v0.z, uv.z, fmaf(v0.w, uv.w, g0))));
            g1v = fmaf(v1.x, uv.x, fmaf(v1.y, uv.y, fmaf(v1.z, uv.z, fmaf(v1.w, uv.w, g1v))));
        }
        sred[(2 * g) * 256 + wl * 64 + L] = g0;
        sred[(2 * g + 1) * 256 + wl * 64 + L] = g1v;
    }
    __syncthreads();                                  // (5) sred ready
    if (t < 256) {
        int h = t & 63, sj = t >> 6;
        const float* sr = sred + sj * 256;
        float gg = sr[h] + sr[64 + h] + sr[128 + h] + sr[192 + h];
        int o = (b * 64 + jp * 4 + sj) * 64 + h;
        float hvv = hv0[o] + gg * (1.0f / 63.0f) + c2_0[h];
        hv1[o] = hvv;
        shv[sj * 64 + h] = hvv;
    }
    __syncthreads();                                  // (6) shv ready; sred dead
    // tail B: p1' dots, w1nT columns shared
    {
        const float4* wv4 = (const float4*)(w1nT + L * 64 + wl * 16);
        const float4* h0 = (const float4*)(shv + (2 * g) * 64 + wl * 16);
        const float4* h1 = (const float4*)(shv + (2 * g + 1) * 64 + wl * 16);
        float pa = 0.f, pb = 0.f;
        #pragma unroll
        for (int m4 = 0; m4 < 4; ++m4) {
            float4 wv = wv4[m4], v0 = h0[m4], v1 = h1[m4];
            pa = fmaf(v0.x, wv.x, fmaf(v0.y, wv.y, fmaf(v0.z, wv.z, fmaf(v0.w, wv.w, pa))));
            pb = fmaf(v1.x, wv.x, fmaf(v1.y, wv.y, fmaf(v1.z, wv.z, fmaf(v1.w, wv.w, pb))));
        }
        sred[(2 * g) * 256 + wl * 64 + L] = pa;       // disjoint from shv region
        sred[(2 * g + 1) * 256 + wl * 64 + L] = pb;
    }
    __syncthreads();                                  // (7) sred ready
    if (t < 256) {
        int h = t & 63, sj = t >> 6;
        const float* sr = sred + sj * 256;
        p1[(b * 64 + jp * 4 + sj) * 64 + h] = biasC[h] + sr[h] + sr[64 + h] + sr[128 + h] + sr[192 + h];
    }
}

__global__ __launch_bounds__(512, 8) void k_L1(
    const u16* __restrict__ he0g,
    const float* __restrict__ p1,        // p1' (biasC folded), per (b,i)
    const float* __restrict__ biasD,
    const float* __restrict__ u2_1T, const float* __restrict__ c2_1,
    const _Float16* __restrict__ WF,
    const float* __restrict__ hv1,
    const float* __restrict__ hw1T, const float* __restrict__ hb1,
    const float* __restrict__ hw2, const float* __restrict__ hb2,
    const float* __restrict__ scale, float* __restrict__ dx)
{
    __shared__ __align__(16) char smem[4 * TILEB + 1024];
    float* sS   = (float*)(smem + 4 * TILEB);
    float* sred = (float*)smem;                  // aliases tile0
    float* shv  = (float*)(smem + TILEB);        // aliases tile1

    int t = threadIdx.x, L = t & 63;
    int wl = __builtin_amdgcn_readfirstlane((t >> 6) & 3);
    int g  = __builtin_amdgcn_readfirstlane(t >> 8);
    int nn = L & 15, quad = L >> 4;
    int c = wl * 16 + nn;
    int cw = c ^ (quad << 3);
    int b = blockIdx.x >> 4, jp = blockIdx.x & 15;
    int ja = jp * 4 + g * 2, jb = ja + 1;
    _Float16* tX0 = (_Float16*)(smem + (2 * g) * TILEB);
    _Float16* tX1 = (_Float16*)(smem + (2 * g + 1) * TILEB);

    {   // Y load: 4 tiles, linear float4 copy
        const float4* src = (const float4*)(he0g + (size_t)(b * 64 + jp * 4) * HBLK);
        float4* dst = (float4*)smem;
        for (int q = t; q < 2304; q += 512) dst[q] = src[q];
    }
    __syncthreads();                                  // (1) Y ready

    floatx4 acc0[4], acc1[4];
    // M3: z1 = p1' + Y @ SC (p1 rows shared across j)
    init_p(acc0, p1, b * 64, c, quad);
    #pragma unroll
    for (int mt = 0; mt < 4; ++mt) acc1[mt] = acc0[mt];
    mfma_acc2(tX0, tX1, WF, 2, c, quad, nn, acc0, acc1);
    __syncthreads();                                  // (2) tile reads done
    #pragma unroll
    for (int mt = 0; mt < 4; ++mt)
        #pragma unroll
        for (int r = 0; r < 4; ++r) {
            int i = mt * 16 + quad * 4 + r;
            tX0[i * TS + cw] = (_Float16)gelu_f(acc0[mt][r]);
            tX1[i * TS + cw] = (_Float16)gelu_f(acc1[mt][r]);
        }
    __syncthreads();                                  // (3) Y2 visible
    // M4: a = gelu(Y2 @ SD + biasD); masked i-sums
    {
        float bd = biasD[c];
        init_bias(acc0, bd); init_bias(acc1, bd);
    }
    mfma_acc2(tX0, tX1, WF, 3, c, quad, nn, acc0, acc1);
    {
        float s0 = 0.f, s1 = 0.f;
        #pragma unroll
        for (int mt = 0; mt < 4; ++mt)
            #pragma unroll
            for (int r = 0; r < 4; ++r) {
                int i = mt * 16 + quad * 4 + r;
                s0 += (i == ja) ? 0.f : gelu_f(acc0[mt][r]);
                s1 += (i == jb) ? 0.f : gelu_f(acc1[mt][r]);
            }
        s0 += __shfl_xor(s0, 16); s0 += __shfl_xor(s0, 32);
        s1 += __shfl_xor(s1, 16); s1 += __shfl_xor(s1, 32);
        if (quad == 0) { sS[(2 * g) * 64 + c] = s0; sS[(2 * g + 1) * 64 + c] = s1; }
    }
    __syncthreads();                                  // (4) sS ready; aliases live
    // tail A: hv2 dots
    {
        const float4* uv4 = (const float4*)(u2_1T + L * 64 + wl * 16);
        const float4* sv0 = (const float4*)(sS + (2 * g) * 64 + wl * 16);
        const float4* sv1 = (const float4*)(sS + (2 * g + 1) * 64 + wl * 16);
        float g0 = 0.f, g1v = 0.f;
        #pragma unroll
        for (int m4 = 0; m4 < 4; ++m4) {
            float4 uv = uv4[m4], v0 = sv0[m4], v1 = sv1[m4];
            g0  = fmaf(v0.x, uv.x, fmaf(v0.y, uv.y, fmaf(v0.z, uv.z, fmaf(v0.w, uv.w, g0))));
            g1v = fmaf(v1.x, uv.x, fmaf(v1.y, uv.y, fmaf(v1.z, uv.z, fmaf(v1.w, uv.w, g1v))));
        }
        sred[(2 * g) * 256 + wl * 64 + L] = g0;
        sred[(2 * g + 1) * 256 + wl * 64 + L] = g1v;
    }
    __syncthreads();                                  // (5) sred ready
    if (t < 256) {
        int h = t & 63, sj = t >> 6;
        const float* sr = sred + sj * 256;
        float gg = sr[h] + sr[64 + h] + sr[128 + h] + sr[192 + h];
        float hv2 = hv1[(b * 64 + jp * 4 + sj) * 64 + h] + gg * (1.0f / 63.0f) + c2_1[h];
        shv[sj * 64 + h] = hv2;
    }
    __syncthreads();                                  // (6) shv ready
    // tail B: head layer-1 dots
    {
        const float4* wv4 = (const float4*)(hw1T + L * 64 + wl * 16);
        const float4* h0 = (const float4*)(shv + (2 * g) * 64 + wl * 16);
        const float4* h1 = (const float4*)(shv + (2 * g + 1) * 64 + wl * 16);
        float a0 = 0.f, a1 = 0.f;
        #pragma unroll
        for (int m4 = 0; m4 < 4; ++m4) {
            float4 wv = wv4[m4], v0 = h0[m4], v1 = h1[m4];
            a0 = fmaf(v0.x, wv.x, fmaf(v0.y, wv.y, fmaf(v0.z, wv.z, fmaf(v0.w, wv.w, a0))));
            a1 = fmaf(v1.x, wv.x, fmaf(v1.y, wv.y, fmaf(v1.z, wv.z, fmaf(v1.w, wv.w, a1))));
        }
        sred[(2 * g) * 256 + wl * 64 + L] = a0;
        sred[(2 * g + 1) * 256 + wl * 64 + L] = a1;
    }
    __syncthreads();                                  // (7) sred ready
    if (t < 256) {
        int h = t & 63, sj = t >> 6;   // wave sj -> j = jp*4+sj
        const float* sr = sred + sj * 256;
        float a = hb1[h] + sr[h] + sr[64 + h] + sr[128 + h] + sr[192 + h];
        float t1 = tanhf(a);
        float dd0 = t1 * hw2[h * 2], dd1 = t1 * hw2[h * 2 + 1];
        #pragma unroll
        for (int off = 1; off <= 32; off <<= 1) { dd0 += __shfl_xor(dd0, off); dd1 += __shfl_xor(dd1, off); }
        if (h == 0) {
            float sp = log1pf(__expf(scale[0]));
            dx[(b * 64 + jp * 4 + sj) * 2 + 0] = (dd0 + hb2[0]) * sp;
            dx[(b * 64 + jp * 4 + sj) * 2 + 1] = (dd1 + hb2[1]) * sp;
        }
    }
}

__global__ __launch_bounds__(64) void k_mean(
    const float* __restrict__ dx, float* __restrict__ out)
{
    __shared__ float s0[64], s1[64];
    int b = blockIdx.x, j = threadIdx.x;
    float2 d = ((const float2*)dx)[b * 64 + j];
    s0[j] = d.x; s1[j] = d.y;
    __syncthreads();
    float m0 = 0.f, m1 = 0.f;
    for (int q = 0; q < 64; ++q) { m0 += s0[q]; m1 += s1[q]; }
    ((float2*)out)[b * 64 + j] = make_float2(d.x - m0 * (1.0f / 64.0f), d.y - m1 * (1.0f / 64.0f));
}

__global__ void k_beacon(float* out, float code) { out[0] = code; }

extern "C" void kernel_launch(void* const* d_in, const int* in_sizes, int n_in,
                              void* d_out, int out_size, void* d_ws, size_t ws_size,
                              hipStream_t stream)
{
    static const int exp_sizes[23] = {
        16384, 8192, 192, 64, 4096, 64,
        256, 64, 4096, 64,
        16384, 128, 8192, 128,
        8192, 128, 8192, 128,
        4096, 64, 128, 2, 1
    };
    // ws layout
    float* hv0 = (float*)d_ws;                  // 524288 f
    float* hv1 = hv0 + 524288;
    float* p0  = hv1 + 524288;
    float* p1  = p0  + 524288;
    float* dx  = p1  + 524288;                  // 16384 f
    float* u2_0T = dx + 16384;                  // 4096 f
    float* u2_1T = u2_0T + 4096;
    float* w1nT  = u2_1T + 4096;
    float* hw1T  = w1nT + 4096;
    float* biasB = hw1T + 4096;                 // 3 x 64 f
    float* biasC = biasB + 64;
    float* biasD = biasC + 64;
    _Float16* WF = (_Float16*)(biasD + 64);     // 16384 f16 (4 stages)
    u16* he0g  = (u16*)(WF + 16384);            // 8192*4608 u16 (75.5 MB)
    const size_t need = (size_t)((char*)(he0g + (size_t)8192 * HBLK) - (char*)d_ws);

    int bad = -1;
    if (n_in != 23 || out_size != 16384) bad = 98;
    else if (ws_size < need) bad = 97;
    else for (int i = 0; i < 23; ++i)
        if (in_sizes[i] != exp_sizes[i]) { bad = i; break; }
    if (bad >= 0) {
        k_beacon<<<1, 1, 0, stream>>>((float*)d_out, 2e6f + bad * 1e4f);
        return;
    }

    const float* x      = (const float*)d_in[0];
    const float* spin   = (const float*)d_in[1];
    const float* nw1    = (const float*)d_in[2];
    const float* nb1    = (const float*)d_in[3];
    const float* nw2    = (const float*)d_in[4];
    const float* nb2    = (const float*)d_in[5];
    const float* ew1    = (const float*)d_in[6];
    const float* eb1    = (const float*)d_in[7];
    const float* ew2    = (const float*)d_in[8];
    const float* eb2    = (const float*)d_in[9];
    const float* v2e_w1 = (const float*)d_in[10];
    const float* v2e_b1 = (const float*)d_in[11];
    const float* v2e_w2 = (const float*)d_in[12];
    const float* v2e_b2 = (const float*)d_in[13];
    const float* e2v_w1 = (const float*)d_in[14];
    const float* e2v_b1 = (const float*)d_in[15];
    const float* e2v_w2 = (const float*)d_in[16];
    const float* e2v_b2 = (const float*)d_in[17];
    const float* hw1    = (const float*)d_in[18];
    const float* hb1    = (const float*)d_in[19];
    const float* hw2    = (const float*)d_in[20];
    const float* hb2    = (const float*)d_in[21];
    const float* scale  = (const float*)d_in[22];

    // layer slices: w1he_l = v2e_w1 + l*8192 + 4096 (edge part); w1n_l = v2e_w1 + l*8192
    k_pre<<<2177, 256, 0, stream>>>(
        ew2, v2e_w1 + 4096, v2e_w2, e2v_w1,
        v2e_w1 + 12288, v2e_w2 + 4096, e2v_w1 + 4096,
        eb2, v2e_b2, e2v_b1, v2e_b2 + 64, e2v_b1 + 64,
        v2e_b1, v2e_b1 + 64,
        e2v_w2, e2v_w2 + 4096, v2e_w1 + 8192, hw1,
        WF, biasB, biasC, biasD,
        u2_0T, u2_1T, w1nT, hw1T,
        x, spin, nw1, nb1, nw2, nb2, v2e_w1, hv0, p0);
    k_L0<<<2048, 512, 0, stream>>>(x, ew1, eb1,
        p0, biasB, u2_0T, e2v_b2,
        WF, hv0, hv1,
        w1nT, biasC, p1,
        he0g);
    k_L1<<<2048, 512, 0, stream>>>(he0g,
        p1, biasD, u2_1T, e2v_b2 + 64,
        WF, hv1, hw1T, hb1, hw2, hb2, scale, dx);
    k_mean<<<128, 64, 0, stream>>>(dx, (float*)d_out);
}

// Round 11
// 207.770 us; speedup vs baseline: 1.0134x; 1.0134x over previous
//
#include <hip/hip_runtime.h>
#include <math.h>

// B=128, N=64, D=2, H=64, M=64, L=2. f32 in / f32 out.
// R28 = byte-identical resubmit of R25/R27 (verified best: 205.6us, k_L0 57.9,
// Round-8 measurement). Round-10 bench died on container infrastructure
// ("failed twice") — no counters; same transient as Round 0, which resolved
// on identical resubmit. No riders: lever inventory fully adjudicated.
// Lever inventory (counter-adjudicated, R15-R26):
//  j-amortization: exhausted at 4 (-9.3, -3.2, next projected negative);
//  waves/block: falsified (R26: occ 31->68% but dur WORSE — barrier width);
//  VGPR cap: falsified (R23, compiler picks 32); intra-phase trim: falsified
//  (R19); dbuf barrier removal: falsified (R20); cross-block coherence
//  fusion: triple-falsified (R15/16, R22 — he0g FETCH 10->46MB poison).
// Session optimum config: 4 j's/block, 256 thr, LDS 37.9KB w/ aliased
// sred/shv, linear b128 he0g copy (pads never read).
// Merged weights: SA=ew2@w1he0, SB=w2_0@u1_0(+biasB), SC=w2_0@w1he1, SD=w2_1@u1_1(+biasD);
// p0' carries b1_0+eb2@w1he0; p1' carries b1n+b2_0@w1he1 (biasC).
// MFMA fragment addressing identical to R9-R14 (verified).

typedef unsigned short u16;
typedef unsigned int u32;
typedef _Float16 half8 __attribute__((ext_vector_type(8)));   // 4 VGPR frag
typedef __attribute__((ext_vector_type(4))) float floatx4;

#define TS 72            // LDS tile row stride (f16): 144 B
#define HROW 72          // he0g row stride (u16) — mirrors LDS tile
#define HBLK (64 * HROW) // 4608 u16 per (b,j) tile
#define TILEB (64 * TS * 2)  // 9216 B per LDS tile

// gelu via A&S 7.1.27 rational erf (|eps|<=5e-4), no exp (R14-verified)
__device__ __forceinline__ float gelu_f(float x) {
    float s = fabsf(x) * 0.70710678118654752f;
    float q = fmaf(fmaf(fmaf(fmaf(0.078108f, s, 0.000972f), s, 0.230389f), s, 0.278393f), s, 1.0f);
    float q2 = q * q;
    float r = __builtin_amdgcn_rcpf(q2 * q2);
    float t = 0.5f * x * r;
    return x > 0.f ? x - t : t;
}

// k_pre: unchanged from R21 (verified).
__global__ __launch_bounds__(256) void k_pre(
    const float* __restrict__ ew2, const float* __restrict__ w1he0,
    const float* __restrict__ w2_0, const float* __restrict__ u1_0,
    const float* __restrict__ w1he1, const float* __restrict__ w2_1,
    const float* __restrict__ u1_1,
    const float* __restrict__ eb2, const float* __restrict__ b2_0,
    const float* __restrict__ c1_0, const float* __restrict__ b2_1,
    const float* __restrict__ c1_1,
    const float* __restrict__ b1_0v, const float* __restrict__ b1nv,
    const float* __restrict__ u2_0, const float* __restrict__ u2_1,
    const float* __restrict__ w1n, const float* __restrict__ hw1,
    _Float16* __restrict__ WF,
    float* __restrict__ biasB, float* __restrict__ biasC, float* __restrict__ biasD,
    float* __restrict__ u2_0T, float* __restrict__ u2_1T,
    float* __restrict__ w1nT, float* __restrict__ hw1T,
    const float* __restrict__ x, const float* __restrict__ spin,
    const float* __restrict__ nw1, const float* __restrict__ nb1,
    const float* __restrict__ nw2, const float* __restrict__ nb2,
    const float* __restrict__ w1_0,
    float* __restrict__ hv, float* __restrict__ p0)
{
    int blk = blockIdx.x;
    if (blk < 64) {
        int s = blk >> 4;                               // product id
        int idx = (blk & 15) * 256 + threadIdx.x;       // 0..4095
        int k = idx >> 6, n = idx & 63;
        const float *A, *Bm;
        if (s == 0)      { A = ew2;  Bm = w1he0; }
        else if (s == 1) { A = w2_0; Bm = u1_0;  }
        else if (s == 2) { A = w2_0; Bm = w1he1; }
        else             { A = w2_1; Bm = u1_1;  }
        float acc = 0.f;
        for (int q = 0; q < 64; ++q) acc = fmaf(A[k * 64 + q], Bm[q * 64 + n], acc);
        int kc = k >> 5, qd = (k >> 3) & 3, jj = k & 7;
        WF[(((s * 2 + kc) * 64 + n) * 4 + qd) * 8 + jj] = (_Float16)acc;
    } else if (blk == 64) {
        int s = threadIdx.x >> 6, cc = threadIdx.x & 63;
        if (s > 0) {
            const float *bv, *Bm, *add; float* dst;
            if (s == 1)      { bv = b2_0; Bm = u1_0;  add = c1_0; dst = biasB; }
            else if (s == 2) { bv = b2_0; Bm = w1he1; add = b1nv; dst = biasC; }
            else             { bv = b2_1; Bm = u1_1;  add = c1_1; dst = biasD; }
            float acc = add[cc];
            for (int q = 0; q < 64; ++q) acc = fmaf(bv[q], Bm[q * 64 + cc], acc);
            dst[cc] = acc;
        }
    } else if (blk < 129) {
        int idx = (blk - 65) * 256 + threadIdx.x;       // 0..16383
        int s = idx >> 12, r = idx & 4095, m = r >> 6, tc = r & 63;
        const float* W = s == 0 ? u2_0 : s == 1 ? u2_1 : s == 2 ? w1n : hw1;
        float* WT      = s == 0 ? u2_0T : s == 1 ? u2_1T : s == 2 ? w1nT : hw1T;
        WT[tc * 64 + m] = W[m * 64 + tc];
    } else {
        __shared__ float a[4][64];
        __shared__ float shv[4][64];
        int w = threadIdx.x >> 6, h = threadIdx.x & 63;
        int node = (blk - 129) * 4 + w;
        float2 xv = ((const float2*)x)[node];
        float sp = spin[node];
        float z = fmaf(xv.x, nw1[h], fmaf(xv.y, nw1[64 + h], fmaf(sp, nw1[128 + h], nb1[h])));
        a[w][h] = gelu_f(z);                         // wave-synchronous slice
        float acc = nb2[h];
        for (int k = 0; k < 64; ++k) acc = fmaf(a[w][k], nw2[k * 64 + h], acc);
        hv[node * 64 + h] = acc;
        shv[w][h] = acc;
        // p0' = b1_0 + eb2@w1he0 (biasA fold, inline) + hv@w1_0
        float pa = b1_0v[h];
        for (int q = 0; q < 64; ++q) pa = fmaf(eb2[q], w1he0[q * 64 + h], pa);
        for (int k = 0; k < 64; ++k) pa = fmaf(shv[w][k], w1_0[k * 64 + h], pa);
        p0[node * 64 + h] = pa;
    }
}

// quad-tile MFMA: shared B-fragment, four A-tiles (R9-verified addressing)
__device__ __forceinline__ void mfma_acc4(
    const _Float16* __restrict__ t0, const _Float16* __restrict__ t1,
    const _Float16* __restrict__ t2, const _Float16* __restrict__ t3,
    const _Float16* __restrict__ WF,
    int stage, int c, int quad, int nn,
    floatx4 a0[4], floatx4 a1[4], floatx4 a2[4], floatx4 a3[4])
{
    int sA = ((nn >> 2) & 3) << 3;
    #pragma unroll
    for (int kc = 0; kc < 2; ++kc) {
        half8 bf = *(const half8*)(WF + (((stage * 2 + kc) * 64 + c) * 4 + quad) * 8);
        int k0 = (kc * 32 + quad * 8) ^ sA;
        #pragma unroll
        for (int mt = 0; mt < 4; ++mt) {
            int off = (mt * 16 + nn) * TS + k0;
            a0[mt] = __builtin_amdgcn_mfma_f32_16x16x32_f16(*(const half8*)(t0 + off), bf, a0[mt], 0, 0, 0);
            a1[mt] = __builtin_amdgcn_mfma_f32_16x16x32_f16(*(const half8*)(t1 + off), bf, a1[mt], 0, 0, 0);
            a2[mt] = __builtin_amdgcn_mfma_f32_16x16x32_f16(*(const half8*)(t2 + off), bf, a2[mt], 0, 0, 0);
            a3[mt] = __builtin_amdgcn_mfma_f32_16x16x32_f16(*(const half8*)(t3 + off), bf, a3[mt], 0, 0, 0);
        }
    }
}

__device__ __forceinline__ void init_bias(floatx4 acc[4], float bc) {
    #pragma unroll
    for (int mt = 0; mt < 4; ++mt) acc[mt] = (floatx4){bc, bc, bc, bc};
}
__device__ __forceinline__ void init_p(floatx4 acc[4], const float* __restrict__ p,
                                       int rowbase, int c, int quad) {
    #pragma unroll
    for (int mt = 0; mt < 4; ++mt)
        #pragma unroll
        for (int r = 0; r < 4; ++r)
            acc[mt][r] = p[(rowbase + mt * 16 + quad * 4 + r) * 64 + c];
}

__global__ __launch_bounds__(256, 4) void k_L0(
    const float* __restrict__ x,
    const float* __restrict__ ew1, const float* __restrict__ eb1,
    const float* __restrict__ p0,        // p0' (biasA folded), per (b,i)
    const float* __restrict__ biasB,
    const float* __restrict__ u2_0T, const float* __restrict__ c2_0,
    const _Float16* __restrict__ WF,
    const float* __restrict__ hv0, float* __restrict__ hv1,
    const float* __restrict__ w1nT, const float* __restrict__ biasC,
    float* __restrict__ p1,
    u16* __restrict__ he0g)
{
    __shared__ __align__(16) char smem[4 * TILEB + 1024];   // 37.9 KB
    _Float16* tA0 = (_Float16*)smem;
    _Float16* tA1 = (_Float16*)(smem + TILEB);
    _Float16* tA2 = (_Float16*)(smem + 2 * TILEB);
    _Float16* tA3 = (_Float16*)(smem + 3 * TILEB);
    float* sS   = (float*)(smem + 4 * TILEB);   // [4][64], dedicated
    float* sred = (float*)smem;                  // [4][256] aliases tA0 (barrier-protected)
    float* shv  = (float*)(smem + TILEB);        // [4][64]  aliases tA1 (barrier-protected)

    int t = threadIdx.x, L = t & 63;
    int w = __builtin_amdgcn_readfirstlane(t >> 6);
    int nn = L & 15, quad = L >> 4;
    int c = w * 16 + nn;
    int cw = c ^ (quad << 3);
    int b = blockIdx.x >> 4, jp = blockIdx.x & 15;
    int j0 = jp * 4, j1 = j0 + 1, j2 = j0 + 2, j3 = j0 + 3;

    // geometry: lane = i = L; four destinations
    float2 xi = ((const float2*)x)[b * 64 + L];
    float2 xja = ((const float2*)x)[b * 64 + j0];
    float2 xjb = ((const float2*)x)[b * 64 + j1];
    float2 xjc = ((const float2*)x)[b * 64 + j2];
    float2 xjd = ((const float2*)x)[b * 64 + j3];
    float da0 = xja.x - xi.x, da1 = xja.y - xi.y;
    float db0 = xjb.x - xi.x, db1 = xjb.y - xi.y;
    float dc0 = xjc.x - xi.x, dc1 = xjc.y - xi.y;
    float dd0_ = xjd.x - xi.x, dd1_ = xjd.y - xi.y;
    float r2a = fmaf(da0, da0, da1 * da1), rra = sqrtf(r2a + 1e-12f);
    float r2b = fmaf(db0, db0, db1 * db1), rrb = sqrtf(r2b + 1e-12f);
    float r2c = fmaf(dc0, dc0, dc1 * dc1), rrc = sqrtf(r2c + 1e-12f);
    float r2d = fmaf(dd0_, dd0_, dd1_ * dd1_), rrd = sqrtf(r2d + 1e-12f);
    int swL = ((L >> 2) & 3) << 3;

    // g1 rows for all four j (ew1/eb1 SGPR loads shared)
    #pragma unroll
    for (int mb = 0; mb < 2; ++mb) {
        int m0 = w * 16 + mb * 8;
        half8 ha, hb, hc, hd;
        #pragma unroll
        for (int kk = 0; kk < 8; ++kk) {
            int m = m0 + kk;
            float e0 = ew1[m], e1 = ew1[64 + m], e2 = ew1[128 + m], e3 = ew1[192 + m], e4 = eb1[m];
            ha[kk] = (_Float16)gelu_f(fmaf(da0, e0, fmaf(da1, e1, fmaf(rra, e2, fmaf(r2a, e3, e4)))));
            hb[kk] = (_Float16)gelu_f(fmaf(db0, e0, fmaf(db1, e1, fmaf(rrb, e2, fmaf(r2b, e3, e4)))));
            hc[kk] = (_Float16)gelu_f(fmaf(dc0, e0, fmaf(dc1, e1, fmaf(rrc, e2, fmaf(r2c, e3, e4)))));
            hd[kk] = (_Float16)gelu_f(fmaf(dd0_, e0, fmaf(dd1_, e1, fmaf(rrd, e2, fmaf(r2d, e3, e4)))));
        }
        int o = L * TS + (m0 ^ swL);
        *(half8*)(tA0 + o) = ha;
        *(half8*)(tA1 + o) = hb;
        *(half8*)(tA2 + o) = hc;
        *(half8*)(tA3 + o) = hd;
    }
    __syncthreads();                                  // (1) g1 ready

    floatx4 acc0[4], acc1[4], acc2[4], acc3[4];
    // M1: z0 = p0' + g1 @ SA (p0 rows shared across j)
    init_p(acc0, p0, b * 64, c, quad);
    #pragma unroll
    for (int mt = 0; mt < 4; ++mt) { acc1[mt] = acc0[mt]; acc2[mt] = acc0[mt]; acc3[mt] = acc0[mt]; }
    mfma_acc4(tA0, tA1, tA2, tA3, WF, 0, c, quad, nn, acc0, acc1, acc2, acc3);
    __syncthreads();                                  // (2) tA reads done
    #pragma unroll
    for (int mt = 0; mt < 4; ++mt)
        #pragma unroll
        for (int r = 0; r < 4; ++r) {
            int i = mt * 16 + quad * 4 + r;
            tA0[i * TS + cw] = (_Float16)gelu_f(acc0[mt][r]);
            tA1[i * TS + cw] = (_Float16)gelu_f(acc1[mt][r]);
            tA2[i * TS + cw] = (_Float16)gelu_f(acc2[mt][r]);
            tA3[i * TS + cw] = (_Float16)gelu_f(acc3[mt][r]);
        }
    __syncthreads();                                  // (3) Y visible
    // he0g: linear b128 copy of tiles (incl. pads — never read; R19-safe)
    {
        float4* dst = (float4*)(he0g + (size_t)(b * 64 + j0) * HBLK);
        const float4* src = (const float4*)smem;
        #pragma unroll
        for (int q = 0; q < 9; ++q)
            dst[t + q * 256] = src[t + q * 256];      // 2304 float4 = 4 tiles
    }
    // M2: a = gelu(Y @ SB + biasB); masked i-sums
    {
        float bb = biasB[c];
        init_bias(acc0, bb); init_bias(acc1, bb); init_bias(acc2, bb); init_bias(acc3, bb);
    }
    mfma_acc4(tA0, tA1, tA2, tA3, WF, 1, c, quad, nn, acc0, acc1, acc2, acc3);
    {
        float s0 = 0.f, s1 = 0.f, s2 = 0.f, s3 = 0.f;
        #pragma unroll
        for (int mt = 0; mt < 4; ++mt)
            #pragma unroll
            for (int r = 0; r < 4; ++r) {
                int i = mt * 16 + quad * 4 + r;
                s0 += (i == j0) ? 0.f : gelu_f(acc0[mt][r]);
                s1 += (i == j1) ? 0.f : gelu_f(acc1[mt][r]);
                s2 += (i == j2) ? 0.f : gelu_f(acc2[mt][r]);
                s3 += (i == j3) ? 0.f : gelu_f(acc3[mt][r]);
            }
        s0 += __shfl_xor(s0, 16); s0 += __shfl_xor(s0, 32);
        s1 += __shfl_xor(s1, 16); s1 += __shfl_xor(s1, 32);
        s2 += __shfl_xor(s2, 16); s2 += __shfl_xor(s2, 32);
        s3 += __shfl_xor(s3, 16); s3 += __shfl_xor(s3, 32);
        if (quad == 0) { sS[c] = s0; sS[64 + c] = s1; sS[128 + c] = s2; sS[192 + c] = s3; }
    }
    __syncthreads();                                  // (4) sS ready; tA reads done -> aliases live
    // tail A: hv1 dots, u2_0T columns shared across 4 j
    {
        const float4* uv4 = (const float4*)(u2_0T + L * 64 + w * 16);
        float g0 = 0.f, g1 = 0.f, g2 = 0.f, g3 = 0.f;
        #pragma unroll
        for (int m4 = 0; m4 < 4; ++m4) {
            float4 uv = uv4[m4];
            float4 v0 = ((const float4*)(sS + w * 16))[m4];
            float4 v1 = ((const float4*)(sS + 64 + w * 16))[m4];
            float4 v2 = ((const float4*)(sS + 128 + w * 16))[m4];
            float4 v3 = ((const float4*)(sS + 192 + w * 16))[m4];
            g0 = fmaf(v0.x, uv.x, fmaf(v0.y, uv.y, fmaf(v0.z, uv.z, fmaf(v0.w, uv.w, g0))));
            g1 = fmaf(v1.x, uv.x, fmaf(v1.y, uv.y, fmaf(v1.z, uv.z, fmaf(v1.w, uv.w, g1))));
            g2 = fmaf(v2.x, uv.x, fmaf(v2.y, uv.y, fmaf(v2.z, uv.z, fmaf(v2.w, uv.w, g2))));
            g3 = fmaf(v3.x, uv.x, fmaf(v3.y, uv.y, fmaf(v3.z, uv.z, fmaf(v3.w, uv.w, g3))));
        }
        sred[0 * 256 + w * 64 + L] = g0;
        sred[1 * 256 + w * 64 + L] = g1;
        sred[2 * 256 + w * 64 + L] = g2;
        sred[3 * 256 + w * 64 + L] = g3;
    }
    __syncthreads();                                  // (5) sred ready
    {
        int h = t & 63, sj = t >> 6;
        const float* sr = sred + sj * 256;
        float g = sr[h] + sr[64 + h] + sr[128 + h] + sr[192 + h];
        int o = (b * 64 + j0 + sj) * 64 + h;
        float hvv = hv0[o] + g * (1.0f / 63.0f) + c2_0[h];
        hv1[o] = hvv;
        shv[sj * 64 + h] = hvv;
    }
    __syncthreads();                                  // (6) shv ready
    // tail B: p1' dots, w1nT columns shared
    {
        const float4* wv4 = (const float4*)(w1nT + L * 64 + w * 16);
        float p0_ = 0.f, p1_ = 0.f, p2_ = 0.f, p3_ = 0.f;
        #pragma unroll
        for (int m4 = 0; m4 < 4; ++m4) {
            float4 wv = wv4[m4];
            float4 v0 = ((const float4*)(shv + w * 16))[m4];
            float4 v1 = ((const float4*)(shv + 64 + w * 16))[m4];
            float4 v2 = ((const float4*)(shv + 128 + w * 16))[m4];
            float4 v3 = ((const float4*)(shv + 192 + w * 16))[m4];
            p0_ = fmaf(v0.x, wv.x, fmaf(v0.y, wv.y, fmaf(v0.z, wv.z, fmaf(v0.w, wv.w, p0_))));
            p1_ = fmaf(v1.x, wv.x, fmaf(v1.y, wv.y, fmaf(v1.z, wv.z, fmaf(v1.w, wv.w, p1_))));
            p2_ = fmaf(v2.x, wv.x, fmaf(v2.y, wv.y, fmaf(v2.z, wv.z, fmaf(v2.w, wv.w, p2_))));
            p3_ = fmaf(v3.x, wv.x, fmaf(v3.y, wv.y, fmaf(v3.z, wv.z, fmaf(v3.w, wv.w, p3_))));
        }
        __syncthreads();                              // (7) shv reads done -> sred reusable
        sred[0 * 256 + w * 64 + L] = p0_;
        sred[1 * 256 + w * 64 + L] = p1_;
        sred[2 * 256 + w * 64 + L] = p2_;
        sred[3 * 256 + w * 64 + L] = p3_;
    }
    __syncthreads();                                  // (8) sred ready
    {
        int h = t & 63, sj = t >> 6;
        const float* sr = sred + sj * 256;
        p1[(b * 64 + j0 + sj) * 64 + h] = biasC[h] + sr[h] + sr[64 + h] + sr[128 + h] + sr[192 + h];
    }
}

__global__ __launch_bounds__(256, 4) void k_L1(
    const u16* __restrict__ he0g,
    const float* __restrict__ p1,        // p1' (biasC folded), per (b,i)
    const float* __restrict__ biasD,
    const float* __restrict__ u2_1T, const float* __restrict__ c2_1,
    const _Float16* __restrict__ WF,
    const float* __restrict__ hv1,
    const float* __restrict__ hw1T, const float* __restrict__ hb1,
    const float* __restrict__ hw2, const float* __restrict__ hb2,
    const float* __restrict__ scale, float* __restrict__ dx)
{
    __shared__ __align__(16) char smem[4 * TILEB + 1024];
    _Float16* tA0 = (_Float16*)smem;
    _Float16* tA1 = (_Float16*)(smem + TILEB);
    _Float16* tA2 = (_Float16*)(smem + 2 * TILEB);
    _Float16* tA3 = (_Float16*)(smem + 3 * TILEB);
    float* sS   = (float*)(smem + 4 * TILEB);
    float* sred = (float*)smem;                  // aliases tA0
    float* shv  = (float*)(smem + TILEB);        // aliases tA1

    int t = threadIdx.x, L = t & 63;
    int w = __builtin_amdgcn_readfirstlane(t >> 6);
    int nn = L & 15, quad = L >> 4;
    int c = w * 16 + nn;
    int cw = c ^ (quad << 3);
    int b = blockIdx.x >> 4, jp = blockIdx.x & 15;
    int j0 = jp * 4, j1 = j0 + 1, j2 = j0 + 2, j3 = j0 + 3;

    {   // Y load: 4 tiles, linear float4 copy (pads included, never read)
        const float4* src = (const float4*)(he0g + (size_t)(b * 64 + j0) * HBLK);
        float4* dst = (float4*)smem;
        #pragma unroll
        for (int q = 0; q < 9; ++q)
            dst[t + q * 256] = src[t + q * 256];
    }
    __syncthreads();                                  // (1) Y ready

    floatx4 acc0[4], acc1[4], acc2[4], acc3[4];
    // M3: z1 = p1' + Y @ SC (p1 rows shared across j)
    init_p(acc0, p1, b * 64, c, quad);
    #pragma unroll
    for (int mt = 0; mt < 4; ++mt) { acc1[mt] = acc0[mt]; acc2[mt] = acc0[mt]; acc3[mt] = acc0[mt]; }
    mfma_acc4(tA0, tA1, tA2, tA3, WF, 2, c, quad, nn, acc0, acc1, acc2, acc3);
    __syncthreads();                                  // (2) tA reads done
    #pragma unroll
    for (int mt = 0; mt < 4; ++mt)
        #pragma unroll
        for (int r = 0; r < 4; ++r) {
            int i = mt * 16 + quad * 4 + r;
            tA0[i * TS + cw] = (_Float16)gelu_f(acc0[mt][r]);
            tA1[i * TS + cw] = (_Float16)gelu_f(acc1[mt][r]);
            tA2[i * TS + cw] = (_Float16)gelu_f(acc2[mt][r]);
            tA3[i * TS + cw] = (_Float16)gelu_f(acc3[mt][r]);
        }
    __syncthreads();                                  // (3) Y2 visible
    // M4: a = gelu(Y2 @ SD + biasD); masked i-sums
    {
        float bd = biasD[c];
        init_bias(acc0, bd); init_bias(acc1, bd); init_bias(acc2, bd); init_bias(acc3, bd);
    }
    mfma_acc4(tA0, tA1, tA2, tA3, WF, 3, c, quad, nn, acc0, acc1, acc2, acc3);
    {
        float s0 = 0.f, s1 = 0.f, s2 = 0.f, s3 = 0.f;
        #pragma unroll
        for (int mt = 0; mt < 4; ++mt)
            #pragma unroll
            for (int r = 0; r < 4; ++r) {
                int i = mt * 16 + quad * 4 + r;
                s0 += (i == j0) ? 0.f : gelu_f(acc0[mt][r]);
                s1 += (i == j1) ? 0.f : gelu_f(acc1[mt][r]);
                s2 += (i == j2) ? 0.f : gelu_f(acc2[mt][r]);
                s3 += (i == j3) ? 0.f : gelu_f(acc3[mt][r]);
            }
        s0 += __shfl_xor(s0, 16); s0 += __shfl_xor(s0, 32);
        s1 += __shfl_xor(s1, 16); s1 += __shfl_xor(s1, 32);
        s2 += __shfl_xor(s2, 16); s2 += __shfl_xor(s2, 32);
        s3 += __shfl_xor(s3, 16); s3 += __shfl_xor(s3, 32);
        if (quad == 0) { sS[c] = s0; sS[64 + c] = s1; sS[128 + c] = s2; sS[192 + c] = s3; }
    }
    __syncthreads();                                  // (4) sS ready; aliases live
    // tail A: hv2 dots
    {
        const float4* uv4 = (const float4*)(u2_1T + L * 64 + w * 16);
        float g0 = 0.f, g1 = 0.f, g2 = 0.f, g3 = 0.f;
        #pragma unroll
        for (int m4 = 0; m4 < 4; ++m4) {
            float4 uv = uv4[m4];
            float4 v0 = ((const float4*)(sS + w * 16))[m4];
            float4 v1 = ((const float4*)(sS + 64 + w * 16))[m4];
            float4 v2 = ((const float4*)(sS + 128 + w * 16))[m4];
            float4 v3 = ((const float4*)(sS + 192 + w * 16))[m4];
            g0 = fmaf(v0.x, uv.x, fmaf(v0.y, uv.y, fmaf(v0.z, uv.z, fmaf(v0.w, uv.w, g0))));
            g1 = fmaf(v1.x, uv.x, fmaf(v1.y, uv.y, fmaf(v1.z, uv.z, fmaf(v1.w, uv.w, g1))));
            g2 = fmaf(v2.x, uv.x, fmaf(v2.y, uv.y, fmaf(v2.z, uv.z, fmaf(v2.w, uv.w, g2))));
            g3 = fmaf(v3.x, uv.x, fmaf(v3.y, uv.y, fmaf(v3.z, uv.z, fmaf(v3.w, uv.w, g3))));
        }
        sred[0 * 256 + w * 64 + L] = g0;
        sred[1 * 256 + w * 64 + L] = g1;
        sred[2 * 256 + w * 64 + L] = g2;
        sred[3 * 256 + w * 64 + L] = g3;
    }
    __syncthreads();                                  // (5) sred ready
    {
        int h = t & 63, sj = t >> 6;
        const float* sr = sred + sj * 256;
        float g = sr[h] + sr[64 + h] + sr[128 + h] + sr[192 + h];
        float hv2 = hv1[(b * 64 + j0 + sj) * 64 + h] + g * (1.0f / 63.0f) + c2_1[h];
        shv[sj * 64 + h] = hv2;
    }
    __syncthreads();                                  // (6) shv ready
    // tail B: head layer-1 dots
    {
        const float4* wv4 = (const float4*)(hw1T + L * 64 + w * 16);
        float a0 = 0.f, a1 = 0.f, a2 = 0.f, a3 = 0.f;
        #pragma unroll
        for (int m4 = 0; m4 < 4; ++m4) {
            float4 wv = wv4[m4];
            float4 v0 = ((const float4*)(shv + w * 16))[m4];
            float4 v1 = ((const float4*)(shv + 64 + w * 16))[m4];
            float4 v2 = ((const float4*)(shv + 128 + w * 16))[m4];
            float4 v3 = ((const float4*)(shv + 192 + w * 16))[m4];
            a0 = fmaf(v0.x, wv.x, fmaf(v0.y, wv.y, fmaf(v0.z, wv.z, fmaf(v0.w, wv.w, a0))));
            a1 = fmaf(v1.x, wv.x, fmaf(v1.y, wv.y, fmaf(v1.z, wv.z, fmaf(v1.w, wv.w, a1))));
            a2 = fmaf(v2.x, wv.x, fmaf(v2.y, wv.y, fmaf(v2.z, wv.z, fmaf(v2.w, wv.w, a2))));
            a3 = fmaf(v3.x, wv.x, fmaf(v3.y, wv.y, fmaf(v3.z, wv.z, fmaf(v3.w, wv.w, a3))));
        }
        __syncthreads();                              // (7) shv reads done
        sred[0 * 256 + w * 64 + L] = a0;
        sred[1 * 256 + w * 64 + L] = a1;
        sred[2 * 256 + w * 64 + L] = a2;
        sred[3 * 256 + w * 64 + L] = a3;
    }
    __syncthreads();                                  // (8) sred ready
    {
        int h = t & 63, sj = t >> 6;   // wave sj -> j0+sj
        const float* sr = sred + sj * 256;
        float a = hb1[h] + sr[h] + sr[64 + h] + sr[128 + h] + sr[192 + h];
        float t1 = tanhf(a);
        float dd0 = t1 * hw2[h * 2], dd1 = t1 * hw2[h * 2 + 1];
        #pragma unroll
        for (int off = 1; off <= 32; off <<= 1) { dd0 += __shfl_xor(dd0, off); dd1 += __shfl_xor(dd1, off); }
        if (h == 0) {
            float sp = log1pf(__expf(scale[0]));
            dx[(b * 64 + j0 + sj) * 2 + 0] = (dd0 + hb2[0]) * sp;
            dx[(b * 64 + j0 + sj) * 2 + 1] = (dd1 + hb2[1]) * sp;
        }
    }
}

__global__ __launch_bounds__(64) void k_mean(
    const float* __restrict__ dx, float* __restrict__ out)
{
    __shared__ float s0[64], s1[64];
    int b = blockIdx.x, j = threadIdx.x;
    float2 d = ((const float2*)dx)[b * 64 + j];
    s0[j] = d.x; s1[j] = d.y;
    __syncthreads();
    float m0 = 0.f, m1 = 0.f;
    for (int q = 0; q < 64; ++q) { m0 += s0[q]; m1 += s1[q]; }
    ((float2*)out)[b * 64 + j] = make_float2(d.x - m0 * (1.0f / 64.0f), d.y - m1 * (1.0f / 64.0f));
}

__global__ void k_beacon(float* out, float code) { out[0] = code; }

extern "C" void kernel_launch(void* const* d_in, const int* in_sizes, int n_in,
                              void* d_out, int out_size, void* d_ws, size_t ws_size,
                              hipStream_t stream)
{
    static const int exp_sizes[23] = {
        16384, 8192, 192, 64, 4096, 64,
        256, 64, 4096, 64,
        16384, 128, 8192, 128,
        8192, 128, 8192, 128,
        4096, 64, 128, 2, 1
    };
    // ws layout
    float* hv0 = (float*)d_ws;                  // 524288 f
    float* hv1 = hv0 + 524288;
    float* p0  = hv1 + 524288;
    float* p1  = p0  + 524288;
    float* dx  = p1  + 524288;                  // 16384 f
    float* u2_0T = dx + 16384;                  // 4096 f
    float* u2_1T = u2_0T + 4096;
    float* w1nT  = u2_1T + 4096;
    float* hw1T  = w1nT + 4096;
    float* biasB = hw1T + 4096;                 // 3 x 64 f
    float* biasC = biasB + 64;
    float* biasD = biasC + 64;
    _Float16* WF = (_Float16*)(biasD + 64);     // 16384 f16 (4 stages)
    u16* he0g  = (u16*)(WF + 16384);            // 8192*4608 u16 (75.5 MB)
    const size_t need = (size_t)((char*)(he0g + (size_t)8192 * HBLK) - (char*)d_ws);

    int bad = -1;
    if (n_in != 23 || out_size != 16384) bad = 98;
    else if (ws_size < need) bad = 97;
    else for (int i = 0; i < 23; ++i)
        if (in_sizes[i] != exp_sizes[i]) { bad = i; break; }
    if (bad >= 0) {
        k_beacon<<<1, 1, 0, stream>>>((float*)d_out, 2e6f + bad * 1e4f);
        return;
    }

    const float* x      = (const float*)d_in[0];
    const float* spin   = (const float*)d_in[1];
    const float* nw1    = (const float*)d_in[2];
    const float* nb1    = (const float*)d_in[3];
    const float* nw2    = (const float*)d_in[4];
    const float* nb2    = (const float*)d_in[5];
    const float* ew1    = (const float*)d_in[6];
    const float* eb1    = (const float*)d_in[7];
    const float* ew2    = (const float*)d_in[8];
    const float* eb2    = (const float*)d_in[9];
    const float* v2e_w1 = (const float*)d_in[10];
    const float* v2e_b1 = (const float*)d_in[11];
    const float* v2e_w2 = (const float*)d_in[12];
    const float* v2e_b2 = (const float*)d_in[13];
    const float* e2v_w1 = (const float*)d_in[14];
    const float* e2v_b1 = (const float*)d_in[15];
    const float* e2v_w2 = (const float*)d_in[16];
    const float* e2v_b2 = (const float*)d_in[17];
    const float* hw1    = (const float*)d_in[18];
    const float* hb1    = (const float*)d_in[19];
    const float* hw2    = (const float*)d_in[20];
    const float* hb2    = (const float*)d_in[21];
    const float* scale  = (const float*)d_in[22];

    // layer slices: w1he_l = v2e_w1 + l*8192 + 4096 (edge part); w1n_l = v2e_w1 + l*8192
    k_pre<<<2177, 256, 0, stream>>>(
        ew2, v2e_w1 + 4096, v2e_w2, e2v_w1,
        v2e_w1 + 12288, v2e_w2 + 4096, e2v_w1 + 4096,
        eb2, v2e_b2, e2v_b1, v2e_b2 + 64, e2v_b1 + 64,
        v2e_b1, v2e_b1 + 64,
        e2v_w2, e2v_w2 + 4096, v2e_w1 + 8192, hw1,
        WF, biasB, biasC, biasD,
        u2_0T, u2_1T, w1nT, hw1T,
        x, spin, nw1, nb1, nw2, nb2, v2e_w1, hv0, p0);
    k_L0<<<2048, 256, 0, stream>>>(x, ew1, eb1,
        p0, biasB, u2_0T, e2v_b2,
        WF, hv0, hv1,
        w1nT, biasC, p1,
        he0g);
    k_L1<<<2048, 256, 0, stream>>>(he0g,
        p1, biasD, u2_1T, e2v_b2 + 64,
        WF, hv1, hw1T, hb1, hw2, hb2, scale, dx);
    k_mean<<<128, 64, 0, stream>>>(dx, (float*)d_out);
}